// Round 1
// baseline (539.617 us; speedup 1.0000x reference)
//
#include <hip/hip_runtime.h>
#include <cstdint>
#include <cmath>

typedef __attribute__((ext_vector_type(4))) float f32x4;
typedef __attribute__((ext_vector_type(8))) short s16x8;

#define LOG2E 1.4426950408889634f

__device__ __forceinline__ unsigned short f2bf(float f) {
    unsigned int u = __float_as_uint(f);
    u += 0x7FFFu + ((u >> 16) & 1u);   // round-to-nearest-even
    return (unsigned short)(u >> 16);
}
__device__ __forceinline__ float bf2f(unsigned short s) {
    return __uint_as_float(((unsigned int)s) << 16);
}

// async global->LDS, 16B per lane. LDS dest is wave-uniform base + lane*16.
__device__ __forceinline__ void async_copy16(const void* g, void* l) {
    __builtin_amdgcn_global_load_lds(
        (const __attribute__((address_space(1))) unsigned int*)(uintptr_t)g,
        (__attribute__((address_space(3))) unsigned int*)(uintptr_t)l,
        16, 0, 0);
}

// ---------------- fp32 -> bf16 cast ----------------
__global__ __launch_bounds__(256) void cast_bf16_kernel(const float* __restrict__ in,
                                                        unsigned short* __restrict__ out,
                                                        int n4) {
    int i = blockIdx.x * 256 + threadIdx.x;
    if (i < n4) {
        float4 v = ((const float4*)in)[i];
        ushort4 o;
        o.x = f2bf(v.x); o.y = f2bf(v.y); o.z = f2bf(v.z); o.w = f2bf(v.w);
        ((ushort4*)out)[i] = o;
    }
}

// ---------------- GEMM: C[M,N] = A[M,K] * B[N,K]^T + bias ----------------
// m97 structure: 128x128 tile, BK=32, global_load_lds staging, 4 waves each 64x64.
template <bool BF16_OUT>
__global__ __launch_bounds__(256) void gemm_bt(const unsigned short* __restrict__ A,
                                               const unsigned short* __restrict__ B,
                                               const float* __restrict__ bias,
                                               void* __restrict__ Cout,
                                               int M, int N, int K) {
    __shared__ unsigned short As[128 * 32];
    __shared__ unsigned short Bs[128 * 32];
    const int tid  = threadIdx.x;
    const int lane = tid & 63;
    const int wv   = tid >> 6;
    const int m0 = blockIdx.y * 128;
    const int n0 = blockIdx.x * 128;
    const int w_row = (wv >> 1) * 64;
    const int w_col = (wv & 1) * 64;
    const int fr = lane & 15;          // fragment row (within 16-tile)
    const int fo = (lane >> 4) * 8;    // fragment k-offset
    const int srow = lane >> 2;        // staging: row within 16-row chunk
    const int scol = (lane & 3) * 8;   // staging: k element offset
    const int c0 = wv * 2;             // this wave's 2 chunks

    f32x4 acc[4][4];
    const f32x4 zf = {0.f, 0.f, 0.f, 0.f};
    for (int r = 0; r < 4; ++r)
        for (int c = 0; c < 4; ++c) acc[r][c] = zf;

    for (int k0 = 0; k0 < K; k0 += 32) {
        for (int c = c0; c < c0 + 2; ++c) {
            const unsigned short* gA = A + (size_t)(m0 + c * 16 + srow) * K + (k0 + scol);
            async_copy16(gA, &As[c * 512]);
            const unsigned short* gB = B + (size_t)(n0 + c * 16 + srow) * K + (k0 + scol);
            async_copy16(gB, &Bs[c * 512]);
        }
        __syncthreads();
        s16x8 af[4], bf[4];
        for (int r = 0; r < 4; ++r)
            af[r] = *(const s16x8*)&As[(w_row + r * 16 + fr) * 32 + fo];
        for (int c = 0; c < 4; ++c)
            bf[c] = *(const s16x8*)&Bs[(w_col + c * 16 + fr) * 32 + fo];
        for (int r = 0; r < 4; ++r)
            for (int c = 0; c < 4; ++c)
                acc[r][c] = __builtin_amdgcn_mfma_f32_16x16x32_bf16(af[r], bf[c], acc[r][c], 0, 0, 0);
        __syncthreads();
    }

    // epilogue: C/D layout col=lane&15, row=(lane>>4)*4+reg
    const int rb = (lane >> 4) * 4;
    for (int c = 0; c < 4; ++c) {
        int col = n0 + w_col + c * 16 + fr;
        float bv = bias[col];
        for (int r = 0; r < 4; ++r) {
            int row = m0 + w_row + r * 16 + rb;
            for (int q = 0; q < 4; ++q) {
                float v = acc[r][c][q] + bv;
                if constexpr (BF16_OUT)
                    ((unsigned short*)Cout)[(size_t)(row + q) * N + col] = f2bf(v);
                else
                    ((float*)Cout)[(size_t)(row + q) * N + col] = v;
            }
        }
    }
}

// ---------------- RoPE in-place on q,k halves of qkv (bf16) ----------------
// rot_dim=32 -> D=16 pairs; pair (d, d+16); theta = pos * base^(-d/16)
__global__ __launch_bounds__(256) void rope_kernel(unsigned short* __restrict__ qkv) {
    int g = blockIdx.x * 256 + threadIdx.x;  // 2048 * 1024 items
    int p = g >> 10;
    int i = g & 1023;
    int qk = i >> 9;          // 0 = q, 1 = k
    int rem = i & 511;
    int hh = rem >> 4;        // head
    int d = rem & 15;         // pair index
    size_t base = (size_t)p * 7680 + qk * 2560 + hh * 80 + d;
    float x1 = bf2f(qkv[base]);
    float x2 = bf2f(qkv[base + 16]);
    float freq = expf(-(float)d * 0.57564627324851142f);  // ln(10000)/16
    float th = (float)p * freq;
    float s, c;
    sincosf(th, &s, &c);
    qkv[base]      = f2bf(x1 * c - x2 * s);
    qkv[base + 16] = f2bf(x1 * s + x2 * c);
}

// ---------------- flash attention ----------------
// block = (head, q-tile of 64). 4 waves; wave w owns q rows [q0+16w, q0+16w+16).
// d padded 80->96 for K=32 MFMA steps. Online softmax state in registers.
__global__ __launch_bounds__(256) void flash_kernel(const unsigned short* __restrict__ qkv,
                                                    unsigned short* __restrict__ attn) {
    __shared__ unsigned short Ks[64 * 104];  // keys x d(96, pitch 104)
    __shared__ unsigned short VT[80 * 72];   // d x keys (pitch 72)
    __shared__ unsigned short Ps[4 * 16 * 72];  // per-wave P, 16 q x 64 keys (pitch 72)
    const int h   = blockIdx.x;
    const int qt  = blockIdx.y;
    const int tid = threadIdx.x;
    const int lane = tid & 63;
    const int wv   = tid >> 6;
    const int q0 = qt * 64;
    const int fr = lane & 15;
    const int fg = lane >> 4;
    const float scale = 0.11180339887498949f;  // 1/sqrt(80)

    // Q fragments straight from global (row = q, k-contiguous)
    s16x8 qf[3];
    {
        const unsigned short* qbase = qkv + (size_t)(q0 + wv * 16 + fr) * 7680 + h * 80;
        const s16x8 zs = {0, 0, 0, 0, 0, 0, 0, 0};
        for (int s = 0; s < 3; ++s) {
            int d = 32 * s + fg * 8;
            qf[s] = (d < 80) ? *(const s16x8*)(qbase + d) : zs;
        }
    }
    f32x4 O[5];
    const f32x4 zf = {0.f, 0.f, 0.f, 0.f};
    for (int t = 0; t < 5; ++t) O[t] = zf;
    float m_i[4] = {-1e30f, -1e30f, -1e30f, -1e30f};
    float l_i[4] = {0.f, 0.f, 0.f, 0.f};

    for (int kt = 0; kt <= qt; ++kt) {
        const int k0 = kt * 64;
        // stage K tile: 64 rows x 12 chunks of 8 bf16 (zeros for d>=80)
        for (int ci = tid; ci < 64 * 12; ci += 256) {
            int row = ci / 12;
            int d = (ci % 12) * 8;
            uint4 val = {0u, 0u, 0u, 0u};
            if (d < 80)
                val = *(const uint4*)(qkv + (size_t)(k0 + row) * 7680 + 2560 + h * 80 + d);
            *(uint4*)&Ks[row * 104 + d] = val;
        }
        // stage V transposed: VT[d][key]
        for (int ci = tid; ci < 64 * 10; ci += 256) {
            int row = ci / 10;
            int d0 = (ci % 10) * 8;
            s16x8 vv = *(const s16x8*)(qkv + (size_t)(k0 + row) * 7680 + 5120 + h * 80 + d0);
            for (int j = 0; j < 8; ++j)
                VT[(d0 + j) * 72 + row] = (unsigned short)vv[j];
        }
        __syncthreads();

        // scores: wave's 16 q-rows x 64 keys
        f32x4 sa[4];
        for (int c = 0; c < 4; ++c) {
            sa[c] = zf;
            for (int s = 0; s < 3; ++s) {
                s16x8 kb = *(const s16x8*)&Ks[(c * 16 + fr) * 104 + 32 * s + fg * 8];
                sa[c] = __builtin_amdgcn_mfma_f32_16x16x32_bf16(qf[s], kb, sa[c], 0, 0, 0);
            }
        }
        float sc[4][4];
        const bool diag = (kt == qt);
        for (int c = 0; c < 4; ++c)
            for (int r = 0; r < 4; ++r) {
                float v = sa[c][r] * scale;
                if (diag && (c * 16 + fr) > (wv * 16 + fg * 4 + r)) v = -1e30f;
                sc[c][r] = v;
            }
        // online softmax (rows live in 16-lane groups; xor-shuffle reduce)
        float al[4];
        for (int r = 0; r < 4; ++r) {
            float mx = fmaxf(fmaxf(sc[0][r], sc[1][r]), fmaxf(sc[2][r], sc[3][r]));
            for (int o = 1; o < 16; o <<= 1) mx = fmaxf(mx, __shfl_xor(mx, o, 64));
            float mnew = fmaxf(m_i[r], mx);
            float a = exp2f((m_i[r] - mnew) * LOG2E);
            float rs = 0.f;
            for (int c = 0; c < 4; ++c) {
                float p = exp2f((sc[c][r] - mnew) * LOG2E);
                sc[c][r] = p;
                rs += p;
            }
            for (int o = 1; o < 16; o <<= 1) rs += __shfl_xor(rs, o, 64);
            l_i[r] = l_i[r] * a + rs;
            m_i[r] = mnew;
            al[r] = a;
        }
        // P: C-layout -> row-major LDS (A-layout readable)
        unsigned short* Pw = &Ps[wv * 16 * 72];
        for (int c = 0; c < 4; ++c)
            for (int r = 0; r < 4; ++r)
                Pw[(fg * 4 + r) * 72 + c * 16 + fr] = f2bf(sc[c][r]);
        for (int t = 0; t < 5; ++t)
            for (int r = 0; r < 4; ++r) O[t][r] *= al[r];
        __syncthreads();
        // O += P @ V
        for (int t = 0; t < 5; ++t)
            for (int s2 = 0; s2 < 2; ++s2) {
                s16x8 pa = *(const s16x8*)&Pw[fr * 72 + s2 * 32 + fg * 8];
                s16x8 vb = *(const s16x8*)&VT[(t * 16 + fr) * 72 + s2 * 32 + fg * 8];
                O[t] = __builtin_amdgcn_mfma_f32_16x16x32_bf16(pa, vb, O[t], 0, 0, 0);
            }
        __syncthreads();
    }
    // epilogue: normalize by l and write bf16 attn[L][2560]
    for (int t = 0; t < 5; ++t)
        for (int r = 0; r < 4; ++r) {
            int row = q0 + wv * 16 + fg * 4 + r;
            int col = h * 80 + t * 16 + fr;
            attn[(size_t)row * 2560 + col] = f2bf(O[t][r] / l_i[r]);
        }
}

extern "C" void kernel_launch(void* const* d_in, const int* in_sizes, int n_in,
                              void* d_out, int out_size, void* d_ws, size_t ws_size,
                              hipStream_t stream) {
    const float* x    = (const float*)d_in[0];  // 2048x2560
    const float* wqkv = (const float*)d_in[1];  // 7680x2560
    const float* bqkv = (const float*)d_in[2];  // 7680
    const float* outw = (const float*)d_in[3];  // 2560x2560
    const float* outb = (const float*)d_in[4];  // 2560
    // d_in[5] = mask: causal triu(-1e9) — hardcoded in flash kernel

    unsigned short* xb    = (unsigned short*)d_ws;                  // 2048*2560
    unsigned short* wqkvb = xb    + (size_t)2048 * 2560;            // 7680*2560
    unsigned short* outwb = wqkvb + (size_t)7680 * 2560;            // 2560*2560
    unsigned short* qkvb  = outwb + (size_t)2560 * 2560;            // 2048*7680
    unsigned short* attnb = qkvb  + (size_t)2048 * 7680;            // 2048*2560
    float* out = (float*)d_out;

    cast_bf16_kernel<<<2048 * 2560 / 4 / 256, 256, 0, stream>>>(x, xb, 2048 * 2560 / 4);
    cast_bf16_kernel<<<7680 * 2560 / 4 / 256, 256, 0, stream>>>(wqkv, wqkvb, 7680 * 2560 / 4);
    cast_bf16_kernel<<<2560 * 2560 / 4 / 256, 256, 0, stream>>>(outw, outwb, 2560 * 2560 / 4);

    gemm_bt<true><<<dim3(7680 / 128, 2048 / 128), 256, 0, stream>>>(
        xb, wqkvb, bqkv, (void*)qkvb, 2048, 7680, 2560);

    rope_kernel<<<2048 * 1024 / 256, 256, 0, stream>>>(qkvb);

    flash_kernel<<<dim3(32, 32), 256, 0, stream>>>(qkvb, attnb);

    gemm_bt<false><<<dim3(2560 / 128, 2048 / 128), 256, 0, stream>>>(
        attnb, outwb, outb, (void*)out, 2048, 2560, 2560);
}